// Round 5
// baseline (954.861 us; speedup 1.0000x reference)
//
#include <hip/hip_runtime.h>

// RK4 neural-ODE: f(y) = tanh(y W1 + b1) W2 + b2;  3072 rows x 255 steps.
// One wave per row, wave-synchronous.
//
// ROUND 5: R1-R4 all showed VGPR=84 regardless of occupancy attributes -->
// the weight loads (const __restrict__, loop-invariant) were REMATERIALIZED
// into the loop by the scheduler, making the kernel L1-BW-bound on ~64
// weight reloads per eval. Fix: pin every weight through an empty inline-asm
// ("+v") after loading -- asm defs cannot be rematerialized, so the 131
// weight floats must stay resident in VGPRs. amdgpu_waves_per_eu(2,3) lets
// the allocator choose 3 waves/EU (168 regs) if the set fits, else fall back
// to 2 waves/EU (256 regs) instead of spilling.
// Phase structure unchanged from R4 (8-way j-split phase 2, DPP combine),
// but all-scalar FMAs (pk_fma is half-rate per component => no cycle win).

typedef float f4v __attribute__((ext_vector_type(4)));

// Never-rematerializable register pin: value becomes an opaque asm def.
#define PIN(x) asm("" : "+v"(x))

__device__ __forceinline__ float rl(float v, int lane) {
  return __int_as_float(__builtin_amdgcn_readlane(__float_as_int(v), lane));
}
// tanh(z) with z pre-scaled by 2*log2(e): tanh = 1 - 2/(2^z + 1)
__device__ __forceinline__ float tanh_scaled(float z) {
  float t = __builtin_amdgcn_exp2f(z);
  return fmaf(-2.0f, __builtin_amdgcn_rcpf(t + 1.0f), 1.0f);
}
// quad_perm xor-1 / xor-2 (VALU-pipe cross-lane)
__device__ __forceinline__ float dpp_xor1(float x) {
  return __int_as_float(__builtin_amdgcn_update_dpp(
      0, __float_as_int(x), 0xB1, 0xF, 0xF, true));  // [1,0,3,2]
}
__device__ __forceinline__ float dpp_xor2(float x) {
  return __int_as_float(__builtin_amdgcn_update_dpp(
      0, __float_as_int(x), 0x4E, 0xF, 0xF, true));  // [2,3,0,1]
}

#define REP16(X) \
  X(0) X(1) X(2) X(3) X(4) X(5) X(6) X(7) X(8) X(9) X(10) X(11) X(12) X(13) \
  X(14) X(15)
#define REP32(X) REP16(X) \
  X(16) X(17) X(18) X(19) X(20) X(21) X(22) X(23) X(24) X(25) X(26) X(27)   \
  X(28) X(29) X(30) X(31)

__global__ void __launch_bounds__(256)
__attribute__((amdgpu_waves_per_eu(2, 3)))
rk4_ode_kernel(const float* __restrict__ fp,   // [3072,32]
               const float* __restrict__ ts,   // [256]
               const float* __restrict__ W1,   // [32,128]
               const float* __restrict__ b1,   // [128]
               const float* __restrict__ W2,   // [128,32]
               const float* __restrict__ b2,   // [32]
               float* __restrict__ out) {      // [3072,256,32]
  // per-wave h buffer: 8 chunks of 16 floats at stride 20 (group reads land
  // on disjoint banks; writes at worst 2-way = free)
  __shared__ float smem[4 * 160];

  const int tid = threadIdx.x;
  const int wv  = tid >> 6;
  const int p   = tid & 63;
  const int row = blockIdx.x * 4 + wv;

  const int g  = (p & 3) | ((p >> 5) << 2);   // j-group: lane bits {0,1,5}
  const int j0 = g << 4;                      // 16 j's per group
  const int d0 = p & 0x1C;                    // outputs d0|m, m=0..3

  const float C = 2.885390081777926814f;      // 2*log2(e) folded into W1/b1

  // ---- W1: lane p holds cols j=2p,2p+1 (pre-scaled), PINNED in VGPRs ----
  const float2* W1v = reinterpret_cast<const float2*>(W1);
#define LOADW1(dd) float w1a_##dd, w1b_##dd; {                               \
    const float2 t_ = W1v[dd * 64 + p];                                      \
    w1a_##dd = t_.x * C; w1b_##dd = t_.y * C;                                \
    PIN(w1a_##dd); PIN(w1b_##dd); }
  REP32(LOADW1)
#undef LOADW1
  const float2 b1t = reinterpret_cast<const float2*>(b1)[p];
  float b1a = b1t.x * C, b1b = b1t.y * C;
  PIN(b1a); PIN(b1b);

  // ---- W2: rows [j0,j0+16) x outputs d0..d0+3 (f4 loads), PINNED ----
#define LOADW2(jj) float w2_0_##jj, w2_1_##jj, w2_2_##jj, w2_3_##jj; {       \
    const float4 t_ = *reinterpret_cast<const float4*>(                      \
        W2 + (j0 + jj) * 32 + d0);                                           \
    w2_0_##jj = t_.x; w2_1_##jj = t_.y; w2_2_##jj = t_.z; w2_3_##jj = t_.w;  \
    PIN(w2_0_##jj); PIN(w2_1_##jj); PIN(w2_2_##jj); PIN(w2_3_##jj); }
  REP16(LOADW2)
#undef LOADW2
  float b2l = b2[p & 31];
  PIN(b2l);

  // ---- RK4 state: lane p holds dim d = p&31 (duplicated across halves) ----
  float y0   = fp[row * 32 + (p & 31)];
  float ycur = y0;
  float kacc = 0.0f;

  float* outrow = out + (size_t)row * (256 * 32);
  if (p < 32) outrow[p] = y0;

  // h LDS addressing: h_j stored at float index 20*(j>>4) + (j&15)
  float* hwbase = &smem[wv * 160];
  float* hwr    = hwbase + 20 * (p >> 3) + 2 * (p & 7);       // f2 write
  const f4v* hrd = reinterpret_cast<const f4v*>(hwbase + 20 * g);
  const int pairaddr = (p ^ 32) << 2;

  for (int t = 0; t < 255; ++t) {
    const float dt = ts[t + 1] - ts[t];
#pragma unroll
    for (int st = 0; st < 4; ++st) {
      // ---- phase 1: z_j = C*(b1_j + sum_d y_d W1[d][j]), j=2p,2p+1.
      // 4 independent chains for FMA-latency cover.
      float a0e = b1a, a0o = 0.0f, a1e = b1b, a1o = 0.0f;
#define P1(dd) { const float s_ = rl(ycur, dd);                              \
                 if ((dd) & 1) { a0o = fmaf(s_, w1a_##dd, a0o);              \
                                 a1o = fmaf(s_, w1b_##dd, a1o); }            \
                 else          { a0e = fmaf(s_, w1a_##dd, a0e);              \
                                 a1e = fmaf(s_, w1b_##dd, a1e); } }
      REP32(P1)
#undef P1
      const float a0 = a0e + a0o, a1 = a1e + a1o;
      *reinterpret_cast<float2*>(hwr) =
          make_float2(tanh_scaled(a0), tanh_scaled(a1));
      __builtin_amdgcn_wave_barrier();          // write before reads

      // ---- phase 2: my 16 h's vs 4 output columns (scalar accs) ----
      float acc0 = 0.0f, acc1 = 0.0f, acc2 = 0.0f, acc3 = 0.0f;
#define PACC(hv, jj)                                                         \
      acc0 = fmaf(hv, w2_0_##jj, acc0); acc1 = fmaf(hv, w2_1_##jj, acc1);    \
      acc2 = fmaf(hv, w2_2_##jj, acc2); acc3 = fmaf(hv, w2_3_##jj, acc3);
      {
        const f4v r0 = hrd[0];
        PACC(r0.x, 0)  PACC(r0.y, 1)  PACC(r0.z, 2)  PACC(r0.w, 3)
        const f4v r1 = hrd[1];
        PACC(r1.x, 4)  PACC(r1.y, 5)  PACC(r1.z, 6)  PACC(r1.w, 7)
        const f4v r2 = hrd[2];
        PACC(r2.x, 8)  PACC(r2.y, 9)  PACC(r2.z, 10) PACC(r2.w, 11)
        const f4v r3 = hrd[3];
        PACC(r3.x, 12) PACC(r3.y, 13) PACC(r3.z, 14) PACC(r3.w, 15)
      }
#undef PACC
      __builtin_amdgcn_wave_barrier();          // reads before next write

      // ---- combine: ^1,^2 via DPP (VALU pipe), select m=p&3, then ^32 ----
      float k0 = acc0, k1 = acc1, k2 = acc2, k3 = acc3;
      k0 += dpp_xor1(k0); k1 += dpp_xor1(k1); k2 += dpp_xor1(k2); k3 += dpp_xor1(k3);
      k0 += dpp_xor2(k0); k1 += dpp_xor2(k1); k2 += dpp_xor2(k2); k3 += dpp_xor2(k3);
      const float s01 = (p & 1) ? k1 : k0;
      const float s23 = (p & 1) ? k3 : k2;
      const float ks  = (p & 2) ? s23 : s01;    // partial for d = p&31
      const float k = ks + b2l + __int_as_float(
          __builtin_amdgcn_ds_bpermute(pairaddr, __float_as_int(ks)));

      // ---- RK4 stage combination ----
      if (st == 0) {
        kacc = k;                   ycur = fmaf(0.5f * dt, k, y0);
      } else if (st == 1) {
        kacc = fmaf(2.0f, k, kacc); ycur = fmaf(0.5f * dt, k, y0);
      } else if (st == 2) {
        kacc = fmaf(2.0f, k, kacc); ycur = fmaf(dt, k, y0);
      } else {
        kacc = kacc + k;
        y0   = fmaf(dt * (1.0f / 6.0f), kacc, y0);
        ycur = y0;
      }
    }
    if (p < 32) outrow[(t + 1) * 32 + p] = y0;
  }
}

extern "C" void kernel_launch(void* const* d_in, const int* in_sizes, int n_in,
                              void* d_out, int out_size, void* d_ws, size_t ws_size,
                              hipStream_t stream) {
  const float* fp = (const float*)d_in[0];   // first_point [3,1024,32]
  const float* ts = (const float*)d_in[1];   // time_steps [256]
  const float* W1 = (const float*)d_in[2];   // [32,128]
  const float* b1 = (const float*)d_in[3];   // [128]
  const float* W2 = (const float*)d_in[4];   // [128,32]
  const float* b2 = (const float*)d_in[5];   // [32]
  float* out = (float*)d_out;                // [3,1024,256,32]

  rk4_ode_kernel<<<768, 256, 0, stream>>>(fp, ts, W1, b1, W2, b2, out);
}